// Round 1
// baseline (277.551 us; speedup 1.0000x reference)
//
#include <hip/hip_runtime.h>
#include <math.h>

typedef __attribute__((ext_vector_type(8))) short short8;
typedef __attribute__((ext_vector_type(4))) float f32x4;
typedef __attribute__((ext_vector_type(4))) float float4v;

__device__ __forceinline__ unsigned short f2bf(float f){
  unsigned int u = __float_as_uint(f);
  u += 0x7FFFu + ((u >> 16) & 1u);
  return (unsigned short)(u >> 16);
}

// ---------------------------------------------------------------------------
// prep: Wt_qkv[n][k] = bf16(W_qkv[k][n])  (n<192,k<512)
//       Wt_out[n][k] = bf16(W_out[k][n])  (n<512,k<64)
// ---------------------------------------------------------------------------
__global__ __launch_bounds__(256) void prep_kernel(
    const float* __restrict__ Wqkv, const float* __restrict__ Wout,
    unsigned short* __restrict__ Wtq, unsigned short* __restrict__ Wto)
{
  int idx = blockIdx.x * 256 + threadIdx.x;
  if (idx < 192 * 512) {
    int n = idx >> 9, k = idx & 511;
    Wtq[idx] = f2bf(Wqkv[k * 192 + n]);
  } else {
    int i2 = idx - 192 * 512;           // < 512*64 by grid sizing
    int n = i2 >> 6, k = i2 & 63;
    Wto[i2] = f2bf(Wout[k * 512 + n]);
  }
}

// ---------------------------------------------------------------------------
// qkv: [16384,512] fp32 @ Wt[192,512] bf16 -> q,k [16384,64] bf16, vT [4][64][4096] bf16
// block = 256 thr (4 waves), wave handles 16 rows x 192 cols. grid = 256.
// ---------------------------------------------------------------------------
__global__ __launch_bounds__(256) void qkv_kernel(
    const float* __restrict__ x,
    const unsigned short* __restrict__ Wt,
    unsigned short* __restrict__ qg,
    unsigned short* __restrict__ kg,
    unsigned short* __restrict__ vT)
{
  __shared__ __align__(16) unsigned short vbuf[64][72];
  const int lane = threadIdx.x & 63;
  const int wave = threadIdx.x >> 6;
  const int mrow = lane & 15;
  const int quad = lane >> 4;
  const int m0 = blockIdx.x * 64 + wave * 16;

  f32x4 acc[12];
#pragma unroll
  for (int t = 0; t < 12; t++) acc[t] = (f32x4){0.f, 0.f, 0.f, 0.f};

  const float* xp = x + (size_t)(m0 + mrow) * 512 + quad * 8;
  const unsigned short* wbase = Wt + mrow * 512 + quad * 8;

  for (int kk = 0; kk < 16; kk++) {
    float4v a0 = *(const float4v*)(xp + kk * 32);
    float4v a1 = *(const float4v*)(xp + kk * 32 + 4);
    short8 af;
    af[0] = (short)f2bf(a0[0]); af[1] = (short)f2bf(a0[1]);
    af[2] = (short)f2bf(a0[2]); af[3] = (short)f2bf(a0[3]);
    af[4] = (short)f2bf(a1[0]); af[5] = (short)f2bf(a1[1]);
    af[6] = (short)f2bf(a1[2]); af[7] = (short)f2bf(a1[3]);
#pragma unroll
    for (int t = 0; t < 12; t++) {
      short8 bf = *(const short8*)(wbase + t * 16 * 512 + kk * 32);
      acc[t] = __builtin_amdgcn_mfma_f32_16x16x32_bf16(af, bf, acc[t], 0, 0, 0);
    }
  }

  // epilogue: tiles 0..3 -> q, 4..7 -> k, 8..11 -> v (LDS transpose)
#pragma unroll
  for (int t = 0; t < 4; t++) {
#pragma unroll
    for (int r = 0; r < 4; r++) {
      const int row = m0 + quad * 4 + r;
      const int c16 = t * 16 + mrow;
      qg[(size_t)row * 64 + c16] = f2bf(acc[t][r]);
      kg[(size_t)row * 64 + c16] = f2bf(acc[t + 4][r]);
      vbuf[wave * 16 + quad * 4 + r][c16] = f2bf(acc[t + 8][r]);
    }
  }
  __syncthreads();
  // vT[b][d][s] coalesced write: thread -> d = tid>>2, s-chunk = (tid&3)*16
  const int d  = threadIdx.x >> 2;
  const int s8 = (threadIdx.x & 3) * 16;
  const int bb = blockIdx.x >> 6;
  const int sb = (blockIdx.x * 64) & 4095;
  short8 w0, w1;
#pragma unroll
  for (int i = 0; i < 8; i++) {
    w0[i] = (short)vbuf[s8 + i][d];
    w1[i] = (short)vbuf[s8 + 8 + i][d];
  }
  unsigned short* dst = vT + (size_t)bb * (64 * 4096) + (size_t)d * 4096 + sb + s8;
  *(short8*)(dst) = w0;
  *(short8*)(dst + 8) = w1;
}

// ---------------------------------------------------------------------------
// flash attention + fused out-projection.
// grid = 256 (B*S/64), block = 256 thr = 4 independent waves, 16 q-rows each.
// ---------------------------------------------------------------------------
__global__ __launch_bounds__(256) void attn_kernel(
    const unsigned short* __restrict__ qg,
    const unsigned short* __restrict__ kg,
    const unsigned short* __restrict__ vT,
    const unsigned short* __restrict__ WtO,
    const float* __restrict__ bias,
    float* __restrict__ out)
{
  __shared__ __align__(16) unsigned short pbuf[4][16][72];
  const int lane = threadIdx.x & 63;
  const int wave = threadIdx.x >> 6;
  const int mrow = lane & 15;
  const int quad = lane >> 4;
  const int m0   = blockIdx.x * 64 + wave * 16;   // global q row base of this wave
  const int b    = blockIdx.x >> 6;
  const int sq0  = m0 & 4095;                     // within-batch q row base

  // Q A-frags (held in regs for whole kernel)
  const unsigned short* qp = qg + (size_t)(m0 + mrow) * 64 + quad * 8;
  short8 qf0 = *(const short8*)(qp);
  short8 qf1 = *(const short8*)(qp + 32);

  float m_run[4], l_run[4];
  f32x4 o[4];
#pragma unroll
  for (int r = 0; r < 4; r++) { m_run[r] = -3.0e38f; l_run[r] = 0.f; }
#pragma unroll
  for (int c = 0; c < 4; c++) o[c] = (f32x4){0.f, 0.f, 0.f, 0.f};

  const int nT = (((blockIdx.x & 63) * 64 + 63) >> 5) + 1;   // causal k-tile count (BN=32)
  const float sc2 = 0.125f * 1.4426950408889634f;            // scale * log2(e)
  const unsigned short* kbase = kg + (size_t)b * 4096 * 64 + mrow * 64 + quad * 8;
  const unsigned short* vbase = vT + (size_t)b * (64 * 4096) + (size_t)mrow * 4096 + quad * 8;

  for (int j = 0; j < nT; j++) {
    const int n0 = j * 32;
    // scores: S = Q(16x64) @ K^T, two 16-col subtiles
    f32x4 s0 = (f32x4){0.f, 0.f, 0.f, 0.f};
    f32x4 s1 = (f32x4){0.f, 0.f, 0.f, 0.f};
    const unsigned short* kp = kbase + (size_t)n0 * 64;
    short8 kf00 = *(const short8*)(kp);
    short8 kf01 = *(const short8*)(kp + 32);
    short8 kf10 = *(const short8*)(kp + 16 * 64);
    short8 kf11 = *(const short8*)(kp + 16 * 64 + 32);
    s0 = __builtin_amdgcn_mfma_f32_16x16x32_bf16(qf0, kf00, s0, 0, 0, 0);
    s0 = __builtin_amdgcn_mfma_f32_16x16x32_bf16(qf1, kf01, s0, 0, 0, 0);
    s1 = __builtin_amdgcn_mfma_f32_16x16x32_bf16(qf0, kf10, s1, 0, 0, 0);
    s1 = __builtin_amdgcn_mfma_f32_16x16x32_bf16(qf1, kf11, s1, 0, 0, 0);

    // online softmax, per accumulator row r (row = sq0 + 4*quad + r)
#pragma unroll
    for (int r = 0; r < 4; r++) {
      const int row = sq0 + quad * 4 + r;
      float v0 = (n0 + mrow      <= row) ? s0[r] : -3.0e38f;
      float v1 = (n0 + 16 + mrow <= row) ? s1[r] : -3.0e38f;
      float mt = fmaxf(v0, v1);
      mt = fmaxf(mt, __shfl_xor(mt, 1));
      mt = fmaxf(mt, __shfl_xor(mt, 2));
      mt = fmaxf(mt, __shfl_xor(mt, 4));
      mt = fmaxf(mt, __shfl_xor(mt, 8));
      const float mnew  = fmaxf(m_run[r], mt);
      const float alpha = exp2f((m_run[r] - mnew) * sc2);
      m_run[r] = mnew;
      const float p0 = exp2f((v0 - mnew) * sc2);
      const float p1 = exp2f((v1 - mnew) * sc2);
      float ps = p0 + p1;
      ps += __shfl_xor(ps, 1);
      ps += __shfl_xor(ps, 2);
      ps += __shfl_xor(ps, 4);
      ps += __shfl_xor(ps, 8);
      l_run[r] = l_run[r] * alpha + ps;
#pragma unroll
      for (int c = 0; c < 4; c++) o[c][r] *= alpha;
      // P: C-layout -> LDS (A-layout round-trip; per-wave region, DS in-order)
      pbuf[wave][quad * 4 + r][mrow]      = f2bf(p0);
      pbuf[wave][quad * 4 + r][16 + mrow] = f2bf(p1);
    }
    short8 pf = *(const short8*)&pbuf[wave][mrow][quad * 8];
#pragma unroll
    for (int c = 0; c < 4; c++) {
      const unsigned short* vp = vbase + (size_t)(c * 16) * 4096 + n0;
      short8 vf = *(const short8*)vp;
      o[c] = __builtin_amdgcn_mfma_f32_16x16x32_bf16(pf, vf, o[c], 0, 0, 0);
    }
  }

  // normalize O and round-trip through LDS into A-layout
#pragma unroll
  for (int r = 0; r < 4; r++) {
    const float inv = 1.0f / l_run[r];
#pragma unroll
    for (int c = 0; c < 4; c++)
      pbuf[wave][quad * 4 + r][c * 16 + mrow] = f2bf(o[c][r] * inv);
  }
  short8 of0 = *(const short8*)&pbuf[wave][mrow][quad * 8];
  short8 of1 = *(const short8*)&pbuf[wave][mrow][32 + quad * 8];

  // fused projection: out(16x512) = O(16x64) @ W_out(64x512) + b, in 4 chunks of 128 cols
#pragma unroll
  for (int ch = 0; ch < 4; ch++) {
    f32x4 pr[8];
#pragma unroll
    for (int t = 0; t < 8; t++) pr[t] = (f32x4){0.f, 0.f, 0.f, 0.f};
#pragma unroll
    for (int t = 0; t < 8; t++) {
      const int n = ch * 128 + t * 16 + mrow;
      const unsigned short* wp = WtO + n * 64 + quad * 8;
      short8 w0 = *(const short8*)(wp);
      short8 w1 = *(const short8*)(wp + 32);
      pr[t] = __builtin_amdgcn_mfma_f32_16x16x32_bf16(of0, w0, pr[t], 0, 0, 0);
      pr[t] = __builtin_amdgcn_mfma_f32_16x16x32_bf16(of1, w1, pr[t], 0, 0, 0);
    }
#pragma unroll
    for (int t = 0; t < 8; t++) {
      const int col = ch * 128 + t * 16 + mrow;
      const float bv = bias[col];
#pragma unroll
      for (int r = 0; r < 4; r++) {
        out[(size_t)(m0 + quad * 4 + r) * 512 + col] = pr[t][r] + bv;
      }
    }
  }
}

// ---------------------------------------------------------------------------
extern "C" void kernel_launch(void* const* d_in, const int* in_sizes, int n_in,
                              void* d_out, int out_size, void* d_ws, size_t ws_size,
                              hipStream_t stream) {
  const float* x    = (const float*)d_in[0];   // [4,4096,512]
  const float* Wqkv = (const float*)d_in[1];   // [512,192]
  const float* Wout = (const float*)d_in[2];   // [64,512]
  const float* bout = (const float*)d_in[3];   // [512]
  float* out = (float*)d_out;                  // [4,4096,512] fp32

  unsigned short* q   = (unsigned short*)d_ws;         // 16384*64 bf16 (2 MB)
  unsigned short* k   = q  + 16384 * 64;               // 2 MB
  unsigned short* vT  = k  + 16384 * 64;               // [4][64][4096] 2 MB
  unsigned short* Wtq = vT + 4 * 64 * 4096;            // [192][512] 192 KB
  unsigned short* Wto = Wtq + 192 * 512;               // [512][64]  64 KB
  // total ws: ~6.25 MB

  prep_kernel<<<512, 256, 0, stream>>>(Wqkv, Wout, Wtq, Wto);
  qkv_kernel<<<256, 256, 0, stream>>>(x, Wtq, q, k, vT);
  attn_kernel<<<256, 256, 0, stream>>>(q, k, vT, Wto, bout, out);
}

// Round 2
// 221.268 us; speedup vs baseline: 1.2544x; 1.2544x over previous
//
#include <hip/hip_runtime.h>
#include <math.h>

typedef __attribute__((ext_vector_type(8))) short short8;
typedef __attribute__((ext_vector_type(4))) short short4v;
typedef __attribute__((ext_vector_type(4))) float f32x4;
typedef __attribute__((ext_vector_type(4))) float float4v;

__device__ __forceinline__ unsigned short f2bf(float f){
  unsigned int u = __float_as_uint(f);
  u += 0x7FFFu + ((u >> 16) & 1u);
  return (unsigned short)(u >> 16);
}

#define SC2 0.1803368801111204f   /* 0.125 * log2(e) */

// ---------------------------------------------------------------------------
// prep: Wt_qkv[n][k] = bf16(W_qkv[k][n])  (n<192,k<512)
//       Wt_out[n][k] = bf16(W_out[k][n])  (n<512,k<64)
// ---------------------------------------------------------------------------
__global__ __launch_bounds__(256) void prep_kernel(
    const float* __restrict__ Wqkv, const float* __restrict__ Wout,
    unsigned short* __restrict__ Wtq, unsigned short* __restrict__ Wto)
{
  int idx = blockIdx.x * 256 + threadIdx.x;
  if (idx < 192 * 512) {
    int n = idx >> 9, k = idx & 511;
    Wtq[idx] = f2bf(Wqkv[k * 192 + n]);
  } else {
    int i2 = idx - 192 * 512;           // < 512*64 by grid sizing
    int n = i2 >> 6, k = i2 & 63;
    Wto[i2] = f2bf(Wout[k * 512 + n]);
  }
}

// ---------------------------------------------------------------------------
// qkv: grid = 768 = 3 parts x 256 row-blocks. part 0->q, 1->k, 2->vT.
// block = 256 thr (4 waves), each wave 16 rows x 64 cols of its part.
// ---------------------------------------------------------------------------
__global__ __launch_bounds__(256) void qkv_kernel(
    const float* __restrict__ x,
    const unsigned short* __restrict__ Wt,
    unsigned short* __restrict__ qg,
    unsigned short* __restrict__ kg,
    unsigned short* __restrict__ vT)
{
  __shared__ __align__(16) unsigned short vbuf[64][72];
  const int part = blockIdx.x % 3;     // 0:q 1:k 2:v
  const int rb   = blockIdx.x / 3;     // 0..255
  const int lane = threadIdx.x & 63;
  const int wave = threadIdx.x >> 6;
  const int mrow = lane & 15;
  const int quad = lane >> 4;
  const int mb = rb * 64;              // block row base
  const int m0 = mb + wave * 16;       // wave row base

  f32x4 acc[4];
#pragma unroll
  for (int t = 0; t < 4; t++) acc[t] = (f32x4){0.f, 0.f, 0.f, 0.f};

  const float* xp = x + (size_t)(m0 + mrow) * 512 + quad * 8;
  const unsigned short* wbase = Wt + (part * 64 + mrow) * 512 + quad * 8;

#pragma unroll 2
  for (int kk = 0; kk < 16; kk++) {
    float4v a0 = *(const float4v*)(xp + kk * 32);
    float4v a1 = *(const float4v*)(xp + kk * 32 + 4);
    short8 af;
    af[0] = (short)f2bf(a0[0]); af[1] = (short)f2bf(a0[1]);
    af[2] = (short)f2bf(a0[2]); af[3] = (short)f2bf(a0[3]);
    af[4] = (short)f2bf(a1[0]); af[5] = (short)f2bf(a1[1]);
    af[6] = (short)f2bf(a1[2]); af[7] = (short)f2bf(a1[3]);
#pragma unroll
    for (int t = 0; t < 4; t++) {
      short8 bf = *(const short8*)(wbase + t * 16 * 512 + kk * 32);
      acc[t] = __builtin_amdgcn_mfma_f32_16x16x32_bf16(af, bf, acc[t], 0, 0, 0);
    }
  }

  // stage C tile into LDS (rows = block-local s, cols = d)
#pragma unroll
  for (int t = 0; t < 4; t++)
#pragma unroll
    for (int r = 0; r < 4; r++)
      vbuf[wave * 16 + quad * 4 + r][t * 16 + mrow] = f2bf(acc[t][r]);
  __syncthreads();

  if (part < 2) {
    unsigned short* dst = part ? kg : qg;
    const int row = threadIdx.x >> 2;
    const int seg = (threadIdx.x & 3) * 16;
    short8 w0 = *(const short8*)&vbuf[row][seg];
    short8 w1 = *(const short8*)&vbuf[row][seg + 8];
    unsigned short* p = dst + (size_t)(mb + row) * 64 + seg;
    *(short8*)(p) = w0;
    *(short8*)(p + 8) = w1;
  } else {
    // transpose to vT[b][d][s]
    const int d  = threadIdx.x >> 2;
    const int s8 = (threadIdx.x & 3) * 16;
    const int bb = rb >> 6;
    const int sb = mb & 4095;
    short8 w0, w1;
#pragma unroll
    for (int i = 0; i < 8; i++) {
      w0[i] = (short)vbuf[s8 + i][d];
      w1[i] = (short)vbuf[s8 + 8 + i][d];
    }
    unsigned short* dst = vT + (size_t)bb * (64 * 4096) + (size_t)d * 4096 + sb + s8;
    *(short8*)(dst) = w0;
    *(short8*)(dst + 8) = w1;
  }
}

// ---------------------------------------------------------------------------
// flash attention, split-K. grid = 640: 4 batches x 160 (qblk, chunk) pairs.
// block = 4 waves, wave = 16 q rows x one 1024-key chunk. Writes partial
// (m, l, unnormalized O) per chunk.
// Scores computed TRANSPOSED (S^T = K @ Q^T): state per lane q = lane&15.
// ---------------------------------------------------------------------------
template <bool MASKED>
__device__ __forceinline__ void attn_iter(
    int n0, int sq0, int mrow, int quad, int wave,
    const unsigned short* __restrict__ kbase,
    const unsigned short* __restrict__ vbase,
    const short8& qf0, const short8& qf1,
    float& m_run, float& l_run, f32x4* o,
    unsigned short (*pbuf)[72])
{
  const unsigned short* kp = kbase + (size_t)(n0 + mrow) * 64 + quad * 8;
  short8 kf00 = *(const short8*)(kp);
  short8 kf01 = *(const short8*)(kp + 32);
  short8 kf10 = *(const short8*)(kp + 16 * 64);
  short8 kf11 = *(const short8*)(kp + 16 * 64 + 32);
  f32x4 s0 = (f32x4){0.f, 0.f, 0.f, 0.f};
  f32x4 s1 = (f32x4){0.f, 0.f, 0.f, 0.f};
  s0 = __builtin_amdgcn_mfma_f32_16x16x32_bf16(kf00, qf0, s0, 0, 0, 0);
  s0 = __builtin_amdgcn_mfma_f32_16x16x32_bf16(kf01, qf1, s0, 0, 0, 0);
  s1 = __builtin_amdgcn_mfma_f32_16x16x32_bf16(kf10, qf0, s1, 0, 0, 0);
  s1 = __builtin_amdgcn_mfma_f32_16x16x32_bf16(kf11, qf1, s1, 0, 0, 0);

  float v[8];
#pragma unroll
  for (int r = 0; r < 4; r++) { v[r] = s0[r]; v[4 + r] = s1[r]; }
  if (MASKED) {
    const int q = sq0 + mrow;
#pragma unroll
    for (int r = 0; r < 4; r++) {
      if (n0 + quad * 4 + r      > q) v[r]     = -3.0e38f;
      if (n0 + 16 + quad * 4 + r > q) v[4 + r] = -3.0e38f;
    }
  }
  float mt = v[0];
#pragma unroll
  for (int i = 1; i < 8; i++) mt = fmaxf(mt, v[i]);
  mt = fmaxf(mt, __shfl_xor(mt, 16));
  mt = fmaxf(mt, __shfl_xor(mt, 32));
  const float mnew  = fmaxf(m_run, mt);
  const float alpha = exp2f((m_run - mnew) * SC2);
  m_run = mnew;
  float p[8], ps = 0.f;
#pragma unroll
  for (int i = 0; i < 8; i++) { p[i] = exp2f((v[i] - mnew) * SC2); ps += p[i]; }
  ps += __shfl_xor(ps, 16);
  ps += __shfl_xor(ps, 32);
  l_run = l_run * alpha + ps;
#pragma unroll
  for (int r = 0; r < 4; r++) {
    const float ar = __shfl(alpha, quad * 4 + r, 64);
#pragma unroll
    for (int c = 0; c < 4; c++) o[c][r] *= ar;
  }
  // P[q=mrow][k_rel]: lane holds k_rel = 4*quad+r (+16) -> two b64 writes
  short4v pk0, pk1;
#pragma unroll
  for (int i = 0; i < 4; i++) { pk0[i] = (short)f2bf(p[i]); pk1[i] = (short)f2bf(p[4 + i]); }
  *(short4v*)&pbuf[mrow][quad * 4]      = pk0;
  *(short4v*)&pbuf[mrow][16 + quad * 4] = pk1;
  short8 pf = *(const short8*)&pbuf[mrow][quad * 8];
#pragma unroll
  for (int c = 0; c < 4; c++) {
    const unsigned short* vp = vbase + (size_t)(c * 16 + mrow) * 4096 + n0 + quad * 8;
    short8 vf = *(const short8*)vp;
    o[c] = __builtin_amdgcn_mfma_f32_16x16x32_bf16(pf, vf, o[c], 0, 0, 0);
  }
}

__global__ __launch_bounds__(256) void attn_kernel(
    const unsigned short* __restrict__ qg,
    const unsigned short* __restrict__ kg,
    const unsigned short* __restrict__ vT,
    float* __restrict__ Opart,
    float2* __restrict__ mlpart)
{
  __shared__ __align__(16) unsigned short pbuf[4][16][72];
  const int lane = threadIdx.x & 63;
  const int wave = threadIdx.x >> 6;
  const int mrow = lane & 15;
  const int quad = lane >> 4;

  const int t = blockIdx.x % 160;
  const int b = blockIdx.x / 160;
  int qj, c;
  if (t < 16)      { qj = t;               c = 0; }
  else if (t < 48) { int u = t - 16; qj = 16 + (u >> 1); c = u & 1; }
  else if (t < 96) { int u = t - 48; int q3 = u / 3; qj = 32 + q3; c = u - 3 * q3; }
  else             { int u = t - 96; qj = 48 + (u >> 2); c = u & 3; }

  const int sq0 = qj * 64 + wave * 16;      // within-batch q row base
  const int g0  = b * 4096 + sq0;           // global q row base

  const unsigned short* qp = qg + (size_t)(g0 + mrow) * 64 + quad * 8;
  short8 qf0 = *(const short8*)(qp);
  short8 qf1 = *(const short8*)(qp + 32);

  const int kstart = c << 10;
  const int kend_i = (kstart + 1024 < sq0 + 16) ? (kstart + 1024) : (sq0 + 16);
  int nT = 0, nF = 0;
  if (kend_i > kstart) {
    nT = (kend_i - kstart + 31) >> 5;
    int avail = sq0 + 1 - kstart;
    if (avail > 0) { nF = avail >> 5; if (nF > nT) nF = nT; }
  }

  float m_run = -3.0e38f, l_run = 0.f;
  f32x4 o[4];
#pragma unroll
  for (int ct = 0; ct < 4; ct++) o[ct] = (f32x4){0.f, 0.f, 0.f, 0.f};

  const unsigned short* kbase = kg + (size_t)b * 4096 * 64;
  const unsigned short* vbase = vT + (size_t)b * 64 * 4096;

#pragma unroll 2
  for (int j = 0; j < nF; j++)
    attn_iter<false>(kstart + j * 32, sq0, mrow, quad, wave, kbase, vbase,
                     qf0, qf1, m_run, l_run, o, pbuf[wave]);
  for (int j = nF; j < nT; j++)
    attn_iter<true>(kstart + j * 32, sq0, mrow, quad, wave, kbase, vbase,
                    qf0, qf1, m_run, l_run, o, pbuf[wave]);

  // write partials: O rows g0+4*quad+r, cols ct*16+mrow
  const size_t obase = ((size_t)c * 16384 + g0) * 64;
#pragma unroll
  for (int ct = 0; ct < 4; ct++)
#pragma unroll
    for (int r = 0; r < 4; r++)
      Opart[obase + (size_t)(quad * 4 + r) * 64 + ct * 16 + mrow] = o[ct][r];
  if (quad == 0)
    mlpart[(size_t)c * 16384 + g0 + mrow] = make_float2(m_run, l_run);
}

// ---------------------------------------------------------------------------
// combine partials + fused out-projection.
// grid = 1024 = 256 row-blocks x 4 col-chunks. wave = 16 q rows x 128 cols.
// ---------------------------------------------------------------------------
__global__ __launch_bounds__(256) void combine_kernel(
    const float* __restrict__ Opart,
    const float2* __restrict__ mlpart,
    const unsigned short* __restrict__ WtO,
    const float* __restrict__ bias,
    float* __restrict__ out)
{
  const int lane = threadIdx.x & 63;
  const int wave = threadIdx.x >> 6;
  const int mrow = lane & 15;
  const int quad = lane >> 4;
  const int rb = blockIdx.x >> 2;
  const int ch = blockIdx.x & 3;
  const int g0 = rb * 64 + wave * 16;
  const int sq0 = g0 & 4095;
  const int nc = (sq0 >> 10) + 1;

  float mc[4], lc[4];
  float mstar = -3.0e38f;
  for (int cI = 0; cI < nc; cI++) {
    float2 v = mlpart[(size_t)cI * 16384 + g0 + mrow];
    mc[cI] = v.x; lc[cI] = v.y;
    mstar = fmaxf(mstar, v.x);
  }
  float lstar = 0.f;
  f32x4 A0 = (f32x4){0,0,0,0}, A1 = A0, A2 = A0, A3 = A0;
  for (int cI = 0; cI < nc; cI++) {
    const float w = exp2f((mc[cI] - mstar) * SC2);
    lstar += lc[cI] * w;
    const float* op = Opart + ((size_t)cI * 16384 + g0 + mrow) * 64 + quad * 8;
    f32x4 x0 = *(const f32x4*)(op);
    f32x4 x1 = *(const f32x4*)(op + 4);
    f32x4 x2 = *(const f32x4*)(op + 32);
    f32x4 x3 = *(const f32x4*)(op + 36);
    A0 += x0 * w; A1 += x1 * w; A2 += x2 * w; A3 += x3 * w;
  }
  const float inv = 1.0f / lstar;
  short8 of0, of1;
#pragma unroll
  for (int i = 0; i < 4; i++) {
    of0[i]     = (short)f2bf(A0[i] * inv);
    of0[i + 4] = (short)f2bf(A1[i] * inv);
    of1[i]     = (short)f2bf(A2[i] * inv);
    of1[i + 4] = (short)f2bf(A3[i] * inv);
  }

#pragma unroll
  for (int t = 0; t < 8; t++) {
    const int n = ch * 128 + t * 16 + mrow;
    const unsigned short* wp = WtO + n * 64 + quad * 8;
    short8 w0 = *(const short8*)(wp);
    short8 w1 = *(const short8*)(wp + 32);
    f32x4 pr = (f32x4){0,0,0,0};
    pr = __builtin_amdgcn_mfma_f32_16x16x32_bf16(of0, w0, pr, 0, 0, 0);
    pr = __builtin_amdgcn_mfma_f32_16x16x32_bf16(of1, w1, pr, 0, 0, 0);
    const float bv = bias[n];
#pragma unroll
    for (int r = 0; r < 4; r++)
      out[(size_t)(g0 + quad * 4 + r) * 512 + n] = pr[r] + bv;
  }
}

// ---------------------------------------------------------------------------
extern "C" void kernel_launch(void* const* d_in, const int* in_sizes, int n_in,
                              void* d_out, int out_size, void* d_ws, size_t ws_size,
                              hipStream_t stream) {
  const float* x    = (const float*)d_in[0];   // [4,4096,512]
  const float* Wqkv = (const float*)d_in[1];   // [512,192]
  const float* Wout = (const float*)d_in[2];   // [64,512]
  const float* bout = (const float*)d_in[3];   // [512]
  float* out = (float*)d_out;                  // [4,4096,512] fp32

  unsigned short* q   = (unsigned short*)d_ws;         // 2 MB
  unsigned short* k   = q  + 16384 * 64;               // 2 MB
  unsigned short* vT  = k  + 16384 * 64;               // 2 MB
  unsigned short* Wtq = vT + 4 * 64 * 4096;            // 192 KB
  unsigned short* Wto = Wtq + 192 * 512;               // 64 KB
  float*  Opart = (float*)(Wto + 512 * 64);            // [4][16384][64] fp32 = 16 MB
  float2* mlprt = (float2*)(Opart + 4 * 16384 * 64);   // [4][16384] = 512 KB
  // total ws: ~22.8 MB

  prep_kernel<<<512, 256, 0, stream>>>(Wqkv, Wout, Wtq, Wto);
  qkv_kernel<<<768, 256, 0, stream>>>(x, Wtq, q, k, vT);
  attn_kernel<<<640, 256, 0, stream>>>(q, k, vT, Opart, mlprt);
  combine_kernel<<<1024, 256, 0, stream>>>(Opart, mlprt, Wto, bout, out);
}